// Round 18
// baseline (91.221 us; speedup 1.0000x reference)
//
#include <hip/hip_runtime.h>
#include <hip/hip_bf16.h>
#include <stdint.h>

typedef __bf16 bf16;
typedef bf16 bf16x8 __attribute__((ext_vector_type(8)));
typedef bf16 bf16x4 __attribute__((ext_vector_type(4)));
typedef float f32x4 __attribute__((ext_vector_type(4)));

#define MFMA_16x16x32(a, b, c) __builtin_amdgcn_mfma_f32_16x16x32_bf16((a), (b), (c), 0, 0, 0)

// ---- problem sizes ----
constexpr int B = 16, S = 512, H = 768, NH = 12, DH = 64;
constexpr long NHID = (long)B * S * H;          // 6291456
constexpr long NW = (long)8 * H * H;            // 4718592 per weight tensor
constexpr float LOG2E = 1.4426950408889634f;

// ---- workspace layout (bytes) ----
constexpr size_t XB_OFF = 0;
constexpr size_t XB_SZ  = (size_t)NHID * 2;
constexpr size_t W_SZ   = (size_t)NW * 2;
constexpr size_t WQ_OFF = XB_OFF + XB_SZ;
constexpr size_t WK_OFF = WQ_OFF + W_SZ;
constexpr size_t WV_OFF = WK_OFF + W_SZ;
constexpr size_t PROJ_SZ = (size_t)B * NH * S * DH * 2;  // 12582912
constexpr size_t QB_OFF = WV_OFF + W_SZ;
constexpr size_t KB_OFF = QB_OFF + PROJ_SZ;
constexpr size_t VB_OFF = KB_OFF + PROJ_SZ;              // V^T: [B,NH,DH,S]
constexpr size_t WS_NEED = VB_OFF + PROJ_SZ;

// ---------------- fused f32 -> bf16 convert (hidden + 3 weights) ----------------
__global__ void cvt_all(const float* __restrict__ x,
                        const float* __restrict__ wq, const float* __restrict__ wk,
                        const float* __restrict__ wv,
                        bf16* __restrict__ xb, bf16* __restrict__ wqb,
                        bf16* __restrict__ wkb, bf16* __restrict__ wvb) {
  long i = ((long)blockIdx.x * blockDim.x + threadIdx.x) * 8;
  const float* src;
  bf16* dst;
  long off;
  if (i < NHID)               { src = x;  dst = xb;  off = i; }
  else if (i < NHID + NW)     { src = wq; dst = wqb; off = i - NHID; }
  else if (i < NHID + 2 * NW) { src = wk; dst = wkb; off = i - NHID - NW; }
  else if (i < NHID + 3 * NW) { src = wv; dst = wvb; off = i - NHID - 2 * NW; }
  else return;
  const float4* sp = reinterpret_cast<const float4*>(src + off);
  float4 a = sp[0], b = sp[1];
  bf16x8 o;
  o[0] = (bf16)a.x; o[1] = (bf16)a.y; o[2] = (bf16)a.z; o[3] = (bf16)a.w;
  o[4] = (bf16)b.x; o[5] = (bf16)b.y; o[6] = (bf16)b.z; o[7] = (bf16)b.w;
  *reinterpret_cast<bf16x8*>(dst + off) = o;
}

// ---------------- projection GEMM: 128x192 tile, 768 blocks, 3 blocks/CU ----------------
// 768 blocks = 8 XCD-groups x (2 batches x 3 proj x 4m x 4n), 512 thr = 8 waves.
// BM=128, BN=192, BK=32, dbuf (40KB staging). Waves 2m x 4n, tile 64x48, acc[4][3].
// Epilogue overlay 48KB -> 3 blocks/CU, all 768 blocks resident.
// Q gets (1/sqrt(DH))*log2(e) folded in (exp2-domain softmax downstream).
// V -> V^T [B,NH,DH,S].
__global__ __launch_bounds__(512, 6) void proj_gemm(
    const bf16* __restrict__ Xb,
    const bf16* __restrict__ Wqb, const bf16* __restrict__ Wkb, const bf16* __restrict__ Wvb,
    const float* __restrict__ bq, const float* __restrict__ bk, const float* __restrict__ bv,
    const int* __restrict__ eidx,
    bf16* __restrict__ Qb, bf16* __restrict__ Kb, bf16* __restrict__ Vb)
{
  __shared__ __align__(16) char smem[49152];   // staging 40KB; epilogue overlay 48KB
  bf16* Asb = (bf16*)smem;                     // [2][128*32] = 16KB
  bf16* Bsb = (bf16*)(smem + 16384);           // [2][192*32] = 24KB

  const int xcd = blockIdx.x & 7;
  const int bi  = blockIdx.x >> 3;            // 0..95
  const int b   = xcd * 2 + (bi / 48);        // batch
  const int rem = bi % 48;                    // 3 proj x 16 tiles
  const int proj = rem / 16;
  const int t16 = rem % 16;
  const int m0  = (t16 >> 2) * 128;
  const int n0  = (t16 & 3) * 192;
  const int e = eidx[b];

  const bf16* W = (proj == 0 ? Wqb : (proj == 1 ? Wkb : Wvb)) + (size_t)e * H * H;
  const float* bias = (proj == 0 ? bq : (proj == 1 ? bk : bv)) + (size_t)e * H;
  bf16* Out = (proj == 0 ? Qb : (proj == 1 ? Kb : Vb));
  const float oscale = (proj == 0) ? 0.125f * LOG2E : 1.0f;  // Q in exp2 domain

  const int tid = threadIdx.x;
  const int lane = tid & 63;
  const int wave = tid >> 6;                  // 0..7
  const int wm = wave >> 2, wn = wave & 3;    // 2 x 64 m, 4 x 48 n
  const int r = lane & 15, lg = lane >> 4;

  const bf16* Abase = Xb + ((size_t)b * S + m0) * H;
  const bf16* Bbase = W + (size_t)n0 * H;

  const int srow = lane >> 2;                          // 0..15 within 16-row unit
  const int sg = ((lane & 3) ^ ((lane >> 3) & 3)) * 8; // pre-swizzled source chunk

  auto stage = [&](int kt, int pb) {
    const int k0 = kt * 32;
    // A: 8 units of 16 rows; wave w stages unit w
    const bf16* ga = Abase + (size_t)(wave * 16 + srow) * H + k0 + sg;
    __builtin_amdgcn_global_load_lds(
        (const __attribute__((address_space(1))) void*)ga,
        (__attribute__((address_space(3))) void*)(&Asb[pb * 4096 + wave * 512]), 16, 0, 0);
    // B: 12 units; wave w stages unit w; waves 0-3 also stage 8+w
    const bf16* gb0 = Bbase + (size_t)(wave * 16 + srow) * H + k0 + sg;
    __builtin_amdgcn_global_load_lds(
        (const __attribute__((address_space(1))) void*)gb0,
        (__attribute__((address_space(3))) void*)(&Bsb[pb * 6144 + wave * 512]), 16, 0, 0);
    if (wave < 4) {
      const bf16* gb1 = Bbase + (size_t)((8 + wave) * 16 + srow) * H + k0 + sg;
      __builtin_amdgcn_global_load_lds(
          (const __attribute__((address_space(1))) void*)gb1,
          (__attribute__((address_space(3))) void*)(&Bsb[pb * 6144 + (8 + wave) * 512]), 16, 0, 0);
    }
  };

  f32x4 acc[4][3] = {};

  stage(0, 0);
  __syncthreads();

  const int sz = (r >> 1) & 3;   // read-side swizzle index

  int buf = 0;
#pragma unroll 1
  for (int kt = 0; kt < 24; ++kt) {
    if (kt < 23) stage(kt + 1, buf ^ 1);   // prefetch flies under this tile's MFMAs

    bf16x8 af[4], bfr[3];
#pragma unroll
    for (int mi = 0; mi < 4; ++mi)
      af[mi] = *reinterpret_cast<const bf16x8*>(
          &Asb[buf * 4096 + (wm * 64 + mi * 16 + r) * 32 + ((lg ^ sz) * 8)]);
#pragma unroll
    for (int ni = 0; ni < 3; ++ni)
      bfr[ni] = *reinterpret_cast<const bf16x8*>(
          &Bsb[buf * 6144 + (wn * 48 + ni * 16 + r) * 32 + ((lg ^ sz) * 8)]);
#pragma unroll
    for (int mi = 0; mi < 4; ++mi)
#pragma unroll
      for (int ni = 0; ni < 3; ++ni)
        acc[mi][ni] = MFMA_16x16x32(af[mi], bfr[ni], acc[mi][ni]);

    __syncthreads();   // next tile staged + all waves done with buf
    buf ^= 1;
  }
  // final __syncthreads above: all waves done with staging LDS -> safe to overlay

  if (proj != 2) {
    // Q,K: acc -> per-wave LDS tile (64 rows x 48 cols) -> coalesced stores
    bf16* ep = (bf16*)smem + wave * 3072;    // 64*48 elems (6KB/wave, 48KB total)
#pragma unroll
    for (int ni = 0; ni < 3; ++ni) {
      const int col = ni * 16 + r;                     // 0..47
      const float bb = bias[n0 + wn * 48 + col];
#pragma unroll
      for (int mi = 0; mi < 4; ++mi)
#pragma unroll
        for (int rr = 0; rr < 4; ++rr)
          ep[(mi * 16 + lg * 4 + rr) * 48 + col] = (bf16)((acc[mi][ni][rr] + bb) * oscale);
    }
    // same-wave RAW on private region: lgkmcnt auto-ordering, no barrier needed
    const int rowL = lane >> 3, sub = lane & 7;
    if (sub < 6) {
      const int gcol = n0 + wn * 48 + sub * 8;         // 8-col chunk never straddles a head
      const int nh = gcol >> 6, dh = gcol & 63;
      bf16* gdst = Out + (((size_t)b * NH + nh) * S + m0 + wm * 64) * DH + dh;
#pragma unroll
      for (int pass = 0; pass < 8; ++pass) {
        const int row = pass * 8 + rowL;
        bf16x8 v = *reinterpret_cast<const bf16x8*>(&ep[row * 48 + sub * 8]);
        *reinterpret_cast<bf16x8*>(&gdst[(size_t)row * DH]) = v;
      }
    }
  } else {
    // V^T: [B,NH,DH,S]; 4 consecutive rows -> vector store
#pragma unroll
    for (int ni = 0; ni < 3; ++ni) {
      const int col = n0 + wn * 48 + ni * 16 + r;
      const int nh = col >> 6, dh = col & 63;
      const float bb = bias[col];
      bf16* orow = Out + ((size_t)b * NH + nh) * DH * S + (size_t)dh * S;
#pragma unroll
      for (int mi = 0; mi < 4; ++mi) {
        bf16x4 v;
#pragma unroll
        for (int rr = 0; rr < 4; ++rr) v[rr] = (bf16)(acc[mi][ni][rr] + bb);
        *reinterpret_cast<bf16x4*>(orow + m0 + wm * 64 + mi * 16 + lg * 4) = v;
      }
    }
  }
}

// ---------------- fused attention: exp2-domain softmax, QBLK=128, defer-max ----------------
// 768 blocks (192 heads x 4 q-blocks of 128 rows), 256 threads = 4 waves,
// each wave owns 32 q-rows = 2 groups of 16. K/V fragments shared across groups.
// Scores arrive in log2-domain (Q pre-scaled by 0.125*log2e); mask scaled by
// log2e at LDS-load; exp2f maps to raw v_exp_f32 (saves 64 v_mul/iter/wave).
__global__ __launch_bounds__(256, 3) void attn_kernel(
    const bf16* __restrict__ Qb, const bf16* __restrict__ Kb, const bf16* __restrict__ VTb,
    const float* __restrict__ mask, float* __restrict__ out)
{
  __shared__ __align__(16) bf16 Ks[2][64 * 64];
  __shared__ __align__(16) bf16 Vs[2][64 * 64];
  __shared__ float maskS[512];

  const int x = blockIdx.x;
  const int xcd = x & 7;
  const int grp = x >> 3;                    // 0..95
  const int qblk = grp & 3;                  // 4 q-blocks of 128
  const int bh = (grp >> 2) * 8 + xcd;       // bijective over 768 = 8*4*24
  const int b = bh / NH;
  const int h = bh % NH;
  const int tid = threadIdx.x;
  const int wave = tid >> 6;
  const int lane = tid & 63;
  const int r = lane & 15, lg = lane >> 4;
  const int qbase = qblk * 128 + wave * 32;  // this wave's 32 q-rows

  const bf16* Q  = Qb  + (size_t)bh * S * DH;
  const bf16* K  = Kb  + (size_t)bh * S * DH;
  const bf16* VT = VTb + (size_t)bh * DH * S;   // [DH][S]

  for (int i = tid; i < S; i += 256) maskS[i] = mask[b * S + i] * LOG2E;

  const int srowoff = lane >> 3;                 // 0..7
  const int sg = (lane & 7) ^ srowoff;           // pre-swizzled source chunk

  auto stage = [&](int kt, int buf) {
    const int kb = kt * 64;
#pragma unroll
    for (int i = 0; i < 2; ++i) {
      const int c = wave * 2 + i;                // 0..7
      const int row = c * 8 + srowoff;
      const bf16* gk = K + (size_t)(kb + row) * DH + sg * 8;
      __builtin_amdgcn_global_load_lds(
          (const __attribute__((address_space(1))) void*)gk,
          (__attribute__((address_space(3))) void*)(&Ks[buf][c * 512]), 16, 0, 0);
      const bf16* gv = VT + (size_t)row * S + kb + sg * 8;
      __builtin_amdgcn_global_load_lds(
          (const __attribute__((address_space(1))) void*)gv,
          (__attribute__((address_space(3))) void*)(&Vs[buf][c * 512]), 16, 0, 0);
    }
  };

  // hoisted Q fragments for both 16-row groups (Q carries 0.125*log2e scale)
  bf16x8 qf0[2], qf1[2];
#pragma unroll
  for (int g = 0; g < 2; ++g) {
    const bf16* qr = &Q[(size_t)(qbase + g * 16 + r) * DH];
    qf0[g] = *reinterpret_cast<const bf16x8*>(qr + lg * 8);
    qf1[g] = *reinterpret_cast<const bf16x8*>(qr + 32 + lg * 8);
  }

  stage(0, 0);
  __syncthreads();   // drains vmcnt(0)+lgkmcnt(0)

  float mr[2] = {-3.0e38f, -3.0e38f};
  float lr[2] = {0.f, 0.f};
  f32x4 ctx[2][4] = {};
  int buf = 0;

#pragma unroll 1
  for (int kt = 0; kt < 8; ++kt) {
    const int kb = kt * 64;
    if (kt < 7) stage(kt + 1, buf ^ 1);   // prefetch flies under this tile's compute

    // QK^T (swapped) from LDS; K-fragments shared across both q-groups
    f32x4 sa[2][4];
#pragma unroll
    for (int t = 0; t < 4; ++t) {
      const int row = t * 16 + r;
      const int sw = row & 7;
      bf16x8 kf0 = *reinterpret_cast<const bf16x8*>(&Ks[buf][row * 64 + ((lg ^ sw) * 8)]);
      bf16x8 kf1 = *reinterpret_cast<const bf16x8*>(&Ks[buf][row * 64 + (((lg + 4) ^ sw) * 8)]);
#pragma unroll
      for (int g = 0; g < 2; ++g) {
        f32x4 a = {};
        a = MFMA_16x16x32(kf0, qf0[g], a);
        a = MFMA_16x16x32(kf1, qf1[g], a);
        sa[g][t] = a;
      }
    }

    // online softmax per group, exp2 domain, defer-max (THR = 6*log2e)
#pragma unroll
    for (int g = 0; g < 2; ++g) {
      float tmax = -3.0e38f;
#pragma unroll
      for (int t = 0; t < 4; ++t)
#pragma unroll
        for (int rr = 0; rr < 4; ++rr) {
          float s = sa[g][t][rr] + maskS[kb + t * 16 + lg * 4 + rr];
          sa[g][t][rr] = s;
          tmax = fmaxf(tmax, s);
        }
      tmax = fmaxf(tmax, __shfl_xor(tmax, 16));
      tmax = fmaxf(tmax, __shfl_xor(tmax, 32));
      if (!__all(tmax <= mr[g] + 8.656170f)) {
        const float mnew = fmaxf(mr[g], tmax);
        const float scale = exp2f(mr[g] - mnew);
        lr[g] *= scale;
#pragma unroll
        for (int dt = 0; dt < 4; ++dt) ctx[g][dt] *= scale;
        mr[g] = mnew;
      }
      float ps = 0.f;
#pragma unroll
      for (int t = 0; t < 4; ++t)
#pragma unroll
        for (int rr = 0; rr < 4; ++rr) {
          float p = exp2f(sa[g][t][rr] - mr[g]);
          sa[g][t][rr] = p;
          ps += p;
        }
      lr[g] += ps;
    }

    // PV from LDS V^T tile; V-fragments shared across both q-groups
#pragma unroll
    for (int kc = 0; kc < 2; ++kc) {
      bf16x8 pf[2];
#pragma unroll
      for (int g = 0; g < 2; ++g) {
        f32x4 p0 = sa[g][2 * kc], p1 = sa[g][2 * kc + 1];
        bf16x8 o;
        o[0] = (bf16)p0[0]; o[1] = (bf16)p0[1]; o[2] = (bf16)p0[2]; o[3] = (bf16)p0[3];
        o[4] = (bf16)p1[0]; o[5] = (bf16)p1[1]; o[6] = (bf16)p1[2]; o[7] = (bf16)p1[3];
        pf[g] = o;
      }
      const int chunk_lo = kc * 4 + (lg >> 1);
      const int rem = (lg & 1) * 4;              // elements
#pragma unroll
      for (int dt = 0; dt < 4; ++dt) {
        const int row = dt * 16 + r;
        const int sw = row & 7;
        const bf16* vlo = &Vs[buf][row * 64 + ((chunk_lo ^ sw) * 8) + rem];
        const bf16* vhi = &Vs[buf][row * 64 + (((chunk_lo + 2) ^ sw) * 8) + rem];
        bf16x4 lo = *reinterpret_cast<const bf16x4*>(vlo);
        bf16x4 hi = *reinterpret_cast<const bf16x4*>(vhi);
        bf16x8 vf;
        vf[0] = lo[0]; vf[1] = lo[1]; vf[2] = lo[2]; vf[3] = lo[3];
        vf[4] = hi[0]; vf[5] = hi[1]; vf[6] = hi[2]; vf[7] = hi[3];
#pragma unroll
        for (int g = 0; g < 2; ++g)
          ctx[g][dt] = MFMA_16x16x32(vf, pf[g], ctx[g][dt]);
      }
    }

    __syncthreads();   // drains vmcnt (next tile staged) + all waves done with buf
    buf ^= 1;
  }

#pragma unroll
  for (int g = 0; g < 2; ++g) {
    float l = lr[g];
    l += __shfl_xor(l, 16);
    l += __shfl_xor(l, 32);
    const float inv = 1.0f / l;
    float* obase = out + ((size_t)b * S + qbase + g * 16 + r) * H + h * DH;
#pragma unroll
    for (int dt = 0; dt < 4; ++dt) {
      float4 o;
      o.x = ctx[g][dt][0] * inv; o.y = ctx[g][dt][1] * inv;
      o.z = ctx[g][dt][2] * inv; o.w = ctx[g][dt][3] * inv;
      *reinterpret_cast<float4*>(obase + dt * 16 + lg * 4) = o;
    }
  }
}

extern "C" void kernel_launch(void* const* d_in, const int* in_sizes, int n_in,
                              void* d_out, int out_size, void* d_ws, size_t ws_size,
                              hipStream_t stream) {
  const float* hidden = (const float*)d_in[0];
  const float* mask   = (const float*)d_in[1];
  const float* Wq = (const float*)d_in[2];
  const float* bq = (const float*)d_in[3];
  const float* Wk = (const float*)d_in[4];
  const float* bk = (const float*)d_in[5];
  const float* Wv = (const float*)d_in[6];
  const float* bv = (const float*)d_in[7];
  const int* eidx = (const int*)d_in[8];

  if (ws_size < WS_NEED) return;

  char* ws = (char*)d_ws;
  bf16* Xb  = (bf16*)(ws + XB_OFF);
  bf16* Wqb = (bf16*)(ws + WQ_OFF);
  bf16* Wkb = (bf16*)(ws + WK_OFF);
  bf16* Wvb = (bf16*)(ws + WV_OFF);
  bf16* Qbf = (bf16*)(ws + QB_OFF);
  bf16* Kbf = (bf16*)(ws + KB_OFF);
  bf16* Vbf = (bf16*)(ws + VB_OFF);
  float* out = (float*)d_out;

  cvt_all<<<9984, 256, 0, stream>>>(hidden, Wq, Wk, Wv, Xb, Wqb, Wkb, Wvb);
  proj_gemm<<<768, 512, 0, stream>>>(Xb, Wqb, Wkb, Wvb, bq, bk, bv, eidx,
                                     Qbf, Kbf, Vbf);
  attn_kernel<<<768, 256, 0, stream>>>(Qbf, Kbf, Vbf, mask, out);
}

// Round 19
// 86.993 us; speedup vs baseline: 1.0486x; 1.0486x over previous
//
#include <hip/hip_runtime.h>
#include <hip/hip_bf16.h>
#include <stdint.h>

typedef __bf16 bf16;
typedef bf16 bf16x8 __attribute__((ext_vector_type(8)));
typedef bf16 bf16x4 __attribute__((ext_vector_type(4)));
typedef float f32x4 __attribute__((ext_vector_type(4)));

#define MFMA_16x16x32(a, b, c) __builtin_amdgcn_mfma_f32_16x16x32_bf16((a), (b), (c), 0, 0, 0)

// ---- problem sizes ----
constexpr int B = 16, S = 512, H = 768, NH = 12, DH = 64;
constexpr long NHID = (long)B * S * H;          // 6291456
constexpr long NW = (long)8 * H * H;            // 4718592 per weight tensor

// ---- workspace layout (bytes) ----
constexpr size_t XB_OFF = 0;
constexpr size_t XB_SZ  = (size_t)NHID * 2;
constexpr size_t W_SZ   = (size_t)NW * 2;
constexpr size_t WQ_OFF = XB_OFF + XB_SZ;
constexpr size_t WK_OFF = WQ_OFF + W_SZ;
constexpr size_t WV_OFF = WK_OFF + W_SZ;
constexpr size_t PROJ_SZ = (size_t)B * NH * S * DH * 2;  // 12582912
constexpr size_t QB_OFF = WV_OFF + W_SZ;
constexpr size_t KB_OFF = QB_OFF + PROJ_SZ;
constexpr size_t VB_OFF = KB_OFF + PROJ_SZ;              // V^T: [B,NH,DH,S]
constexpr size_t WS_NEED = VB_OFF + PROJ_SZ;

// ---------------- fused f32 -> bf16 convert (hidden + 3 weights) ----------------
__global__ void cvt_all(const float* __restrict__ x,
                        const float* __restrict__ wq, const float* __restrict__ wk,
                        const float* __restrict__ wv,
                        bf16* __restrict__ xb, bf16* __restrict__ wqb,
                        bf16* __restrict__ wkb, bf16* __restrict__ wvb) {
  long i = ((long)blockIdx.x * blockDim.x + threadIdx.x) * 8;
  const float* src;
  bf16* dst;
  long off;
  if (i < NHID)               { src = x;  dst = xb;  off = i; }
  else if (i < NHID + NW)     { src = wq; dst = wqb; off = i - NHID; }
  else if (i < NHID + 2 * NW) { src = wk; dst = wkb; off = i - NHID - NW; }
  else if (i < NHID + 3 * NW) { src = wv; dst = wvb; off = i - NHID - 2 * NW; }
  else return;
  const float4* sp = reinterpret_cast<const float4*>(src + off);
  float4 a = sp[0], b = sp[1];
  bf16x8 o;
  o[0] = (bf16)a.x; o[1] = (bf16)a.y; o[2] = (bf16)a.z; o[3] = (bf16)a.w;
  o[4] = (bf16)b.x; o[5] = (bf16)b.y; o[6] = (bf16)b.z; o[7] = (bf16)b.w;
  *reinterpret_cast<bf16x8*>(dst + off) = o;
}

// ---------------- projection GEMM: 128x192 tile, 768 blocks, 3 blocks/CU ----------------
// 768 blocks = 8 XCD-groups x (2 batches x 3 proj x 4m x 4n), 512 thr = 8 waves.
// BM=128, BN=192, BK=32, dbuf (40KB staging). Waves 2m x 4n, tile 64x48, acc[4][3].
// Epilogue overlay pad 48 -> 48KB LDS -> 3 blocks/CU: ALL 768 blocks resident,
// zero tail rounds, 24 waves/CU TLP.
// Q gets 1/sqrt(DH)=0.125 folded in (exact). V -> V^T [B,NH,DH,S].
__global__ __launch_bounds__(512, 6) void proj_gemm(
    const bf16* __restrict__ Xb,
    const bf16* __restrict__ Wqb, const bf16* __restrict__ Wkb, const bf16* __restrict__ Wvb,
    const float* __restrict__ bq, const float* __restrict__ bk, const float* __restrict__ bv,
    const int* __restrict__ eidx,
    bf16* __restrict__ Qb, bf16* __restrict__ Kb, bf16* __restrict__ Vb)
{
  __shared__ __align__(16) char smem[49152];   // staging 40KB; epilogue overlay 48KB
  bf16* Asb = (bf16*)smem;                     // [2][128*32] = 16KB
  bf16* Bsb = (bf16*)(smem + 16384);           // [2][192*32] = 24KB

  const int xcd = blockIdx.x & 7;
  const int bi  = blockIdx.x >> 3;            // 0..95
  const int b   = xcd * 2 + (bi / 48);        // batch
  const int rem = bi % 48;                    // 3 proj x 16 tiles
  const int proj = rem / 16;
  const int t16 = rem % 16;
  const int m0  = (t16 >> 2) * 128;
  const int n0  = (t16 & 3) * 192;
  const int e = eidx[b];

  const bf16* W = (proj == 0 ? Wqb : (proj == 1 ? Wkb : Wvb)) + (size_t)e * H * H;
  const float* bias = (proj == 0 ? bq : (proj == 1 ? bk : bv)) + (size_t)e * H;
  bf16* Out = (proj == 0 ? Qb : (proj == 1 ? Kb : Vb));
  const float oscale = (proj == 0) ? 0.125f : 1.0f;   // fold 1/sqrt(DH) into Q

  const int tid = threadIdx.x;
  const int lane = tid & 63;
  const int wave = tid >> 6;                  // 0..7
  const int wm = wave >> 2, wn = wave & 3;    // 2 x 64 m, 4 x 48 n
  const int r = lane & 15, lg = lane >> 4;

  const bf16* Abase = Xb + ((size_t)b * S + m0) * H;
  const bf16* Bbase = W + (size_t)n0 * H;

  const int srow = lane >> 2;                          // 0..15 within 16-row unit
  const int sg = ((lane & 3) ^ ((lane >> 3) & 3)) * 8; // pre-swizzled source chunk

  auto stage = [&](int kt, int pb) {
    const int k0 = kt * 32;
    // A: 8 units of 16 rows; wave w stages unit w
    const bf16* ga = Abase + (size_t)(wave * 16 + srow) * H + k0 + sg;
    __builtin_amdgcn_global_load_lds(
        (const __attribute__((address_space(1))) void*)ga,
        (__attribute__((address_space(3))) void*)(&Asb[pb * 4096 + wave * 512]), 16, 0, 0);
    // B: 12 units; wave w stages unit w; waves 0-3 also stage 8+w
    const bf16* gb0 = Bbase + (size_t)(wave * 16 + srow) * H + k0 + sg;
    __builtin_amdgcn_global_load_lds(
        (const __attribute__((address_space(1))) void*)gb0,
        (__attribute__((address_space(3))) void*)(&Bsb[pb * 6144 + wave * 512]), 16, 0, 0);
    if (wave < 4) {
      const bf16* gb1 = Bbase + (size_t)((8 + wave) * 16 + srow) * H + k0 + sg;
      __builtin_amdgcn_global_load_lds(
          (const __attribute__((address_space(1))) void*)gb1,
          (__attribute__((address_space(3))) void*)(&Bsb[pb * 6144 + (8 + wave) * 512]), 16, 0, 0);
    }
  };

  f32x4 acc[4][3] = {};

  stage(0, 0);
  __syncthreads();

  const int sz = (r >> 1) & 3;   // read-side swizzle index

  int buf = 0;
#pragma unroll 1
  for (int kt = 0; kt < 24; ++kt) {
    if (kt < 23) stage(kt + 1, buf ^ 1);   // prefetch flies under this tile's MFMAs

    bf16x8 af[4], bfr[3];
#pragma unroll
    for (int mi = 0; mi < 4; ++mi)
      af[mi] = *reinterpret_cast<const bf16x8*>(
          &Asb[buf * 4096 + (wm * 64 + mi * 16 + r) * 32 + ((lg ^ sz) * 8)]);
#pragma unroll
    for (int ni = 0; ni < 3; ++ni)
      bfr[ni] = *reinterpret_cast<const bf16x8*>(
          &Bsb[buf * 6144 + (wn * 48 + ni * 16 + r) * 32 + ((lg ^ sz) * 8)]);
#pragma unroll
    for (int mi = 0; mi < 4; ++mi)
#pragma unroll
      for (int ni = 0; ni < 3; ++ni)
        acc[mi][ni] = MFMA_16x16x32(af[mi], bfr[ni], acc[mi][ni]);

    __syncthreads();   // next tile staged + all waves done with buf
    buf ^= 1;
  }
  // final __syncthreads above: all waves done with staging LDS -> safe to overlay

  if (proj != 2) {
    // Q,K: acc -> per-wave LDS tile (64 rows x 48 cols, no pad) -> coalesced stores
    bf16* ep = (bf16*)smem + wave * 3072;    // 64*48 elems (6KB/wave, 48KB total)
#pragma unroll
    for (int ni = 0; ni < 3; ++ni) {
      const int col = ni * 16 + r;                     // 0..47
      const float bb = bias[n0 + wn * 48 + col];
#pragma unroll
      for (int mi = 0; mi < 4; ++mi)
#pragma unroll
        for (int rr = 0; rr < 4; ++rr)
          ep[(mi * 16 + lg * 4 + rr) * 48 + col] = (bf16)((acc[mi][ni][rr] + bb) * oscale);
    }
    // same-wave RAW on private region: lgkmcnt auto-ordering, no barrier needed
    const int rowL = lane >> 3, sub = lane & 7;
    if (sub < 6) {
      const int gcol = n0 + wn * 48 + sub * 8;         // 8-col chunk never straddles a head
      const int nh = gcol >> 6, dh = gcol & 63;
      bf16* gdst = Out + (((size_t)b * NH + nh) * S + m0 + wm * 64) * DH + dh;
#pragma unroll
      for (int pass = 0; pass < 8; ++pass) {
        const int row = pass * 8 + rowL;
        bf16x8 v = *reinterpret_cast<const bf16x8*>(&ep[row * 48 + sub * 8]);
        *reinterpret_cast<bf16x8*>(&gdst[(size_t)row * DH]) = v;
      }
    }
  } else {
    // V^T: [B,NH,DH,S]; 4 consecutive rows -> vector store
#pragma unroll
    for (int ni = 0; ni < 3; ++ni) {
      const int col = n0 + wn * 48 + ni * 16 + r;
      const int nh = col >> 6, dh = col & 63;
      const float bb = bias[col];
      bf16* orow = Out + ((size_t)b * NH + nh) * DH * S + (size_t)dh * S;
#pragma unroll
      for (int mi = 0; mi < 4; ++mi) {
        bf16x4 v;
#pragma unroll
        for (int rr = 0; rr < 4; ++rr) v[rr] = (bf16)(acc[mi][ni][rr] + bb);
        *reinterpret_cast<bf16x4*>(orow + m0 + wm * 64 + mi * 16 + lg * 4) = v;
      }
    }
  }
}

// ---------------- fused attention: QBLK=128 + defer-max; Q pre-scaled ----------------
// 768 blocks (192 heads x 4 q-blocks of 128 rows), 256 threads = 4 waves,
// each wave owns 32 q-rows = 2 groups of 16. K/V fragments shared across groups.
__global__ __launch_bounds__(256, 3) void attn_kernel(
    const bf16* __restrict__ Qb, const bf16* __restrict__ Kb, const bf16* __restrict__ VTb,
    const float* __restrict__ mask, float* __restrict__ out)
{
  __shared__ __align__(16) bf16 Ks[2][64 * 64];
  __shared__ __align__(16) bf16 Vs[2][64 * 64];
  __shared__ float maskS[512];

  const int x = blockIdx.x;
  const int xcd = x & 7;
  const int grp = x >> 3;                    // 0..95
  const int qblk = grp & 3;                  // 4 q-blocks of 128
  const int bh = (grp >> 2) * 8 + xcd;       // bijective over 768 = 8*4*24
  const int b = bh / NH;
  const int h = bh % NH;
  const int tid = threadIdx.x;
  const int wave = tid >> 6;
  const int lane = tid & 63;
  const int r = lane & 15, lg = lane >> 4;
  const int qbase = qblk * 128 + wave * 32;  // this wave's 32 q-rows

  const bf16* Q  = Qb  + (size_t)bh * S * DH;
  const bf16* K  = Kb  + (size_t)bh * S * DH;
  const bf16* VT = VTb + (size_t)bh * DH * S;   // [DH][S]

  for (int i = tid; i < S; i += 256) maskS[i] = mask[b * S + i];

  const int srowoff = lane >> 3;                 // 0..7
  const int sg = (lane & 7) ^ srowoff;           // pre-swizzled source chunk

  auto stage = [&](int kt, int buf) {
    const int kb = kt * 64;
#pragma unroll
    for (int i = 0; i < 2; ++i) {
      const int c = wave * 2 + i;                // 0..7
      const int row = c * 8 + srowoff;
      const bf16* gk = K + (size_t)(kb + row) * DH + sg * 8;
      __builtin_amdgcn_global_load_lds(
          (const __attribute__((address_space(1))) void*)gk,
          (__attribute__((address_space(3))) void*)(&Ks[buf][c * 512]), 16, 0, 0);
      const bf16* gv = VT + (size_t)row * S + kb + sg * 8;
      __builtin_amdgcn_global_load_lds(
          (const __attribute__((address_space(1))) void*)gv,
          (__attribute__((address_space(3))) void*)(&Vs[buf][c * 512]), 16, 0, 0);
    }
  };

  // hoisted Q fragments for both 16-row groups (Q already carries 1/8 scale)
  bf16x8 qf0[2], qf1[2];
#pragma unroll
  for (int g = 0; g < 2; ++g) {
    const bf16* qr = &Q[(size_t)(qbase + g * 16 + r) * DH];
    qf0[g] = *reinterpret_cast<const bf16x8*>(qr + lg * 8);
    qf1[g] = *reinterpret_cast<const bf16x8*>(qr + 32 + lg * 8);
  }

  stage(0, 0);
  __syncthreads();   // drains vmcnt(0)+lgkmcnt(0)

  float mr[2] = {-3.0e38f, -3.0e38f};
  float lr[2] = {0.f, 0.f};
  f32x4 ctx[2][4] = {};
  int buf = 0;

#pragma unroll 1
  for (int kt = 0; kt < 8; ++kt) {
    const int kb = kt * 64;
    if (kt < 7) stage(kt + 1, buf ^ 1);   // prefetch flies under this tile's compute

    // QK^T (swapped) from LDS; K-fragments shared across both q-groups
    f32x4 sa[2][4];
#pragma unroll
    for (int t = 0; t < 4; ++t) {
      const int row = t * 16 + r;
      const int sw = row & 7;
      bf16x8 kf0 = *reinterpret_cast<const bf16x8*>(&Ks[buf][row * 64 + ((lg ^ sw) * 8)]);
      bf16x8 kf1 = *reinterpret_cast<const bf16x8*>(&Ks[buf][row * 64 + (((lg + 4) ^ sw) * 8)]);
#pragma unroll
      for (int g = 0; g < 2; ++g) {
        f32x4 a = {};
        a = MFMA_16x16x32(kf0, qf0[g], a);
        a = MFMA_16x16x32(kf1, qf1[g], a);
        sa[g][t] = a;
      }
    }

    // online softmax per group with defer-max (THR=6)
#pragma unroll
    for (int g = 0; g < 2; ++g) {
      float tmax = -3.0e38f;
#pragma unroll
      for (int t = 0; t < 4; ++t)
#pragma unroll
        for (int rr = 0; rr < 4; ++rr) {
          float s = sa[g][t][rr] + maskS[kb + t * 16 + lg * 4 + rr];
          sa[g][t][rr] = s;
          tmax = fmaxf(tmax, s);
        }
      tmax = fmaxf(tmax, __shfl_xor(tmax, 16));
      tmax = fmaxf(tmax, __shfl_xor(tmax, 32));
      if (!__all(tmax <= mr[g] + 6.0f)) {
        const float mnew = fmaxf(mr[g], tmax);
        const float scale = __expf(mr[g] - mnew);
        lr[g] *= scale;
#pragma unroll
        for (int dt = 0; dt < 4; ++dt) ctx[g][dt] *= scale;
        mr[g] = mnew;
      }
      float ps = 0.f;
#pragma unroll
      for (int t = 0; t < 4; ++t)
#pragma unroll
        for (int rr = 0; rr < 4; ++rr) {
          float p = __expf(sa[g][t][rr] - mr[g]);
          sa[g][t][rr] = p;
          ps += p;
        }
      lr[g] += ps;
    }

    // PV from LDS V^T tile; V-fragments shared across both q-groups
#pragma unroll
    for (int kc = 0; kc < 2; ++kc) {
      bf16x8 pf[2];
#pragma unroll
      for (int g = 0; g < 2; ++g) {
        f32x4 p0 = sa[g][2 * kc], p1 = sa[g][2 * kc + 1];
        bf16x8 o;
        o[0] = (bf16)p0[0]; o[1] = (bf16)p0[1]; o[2] = (bf16)p0[2]; o[3] = (bf16)p0[3];
        o[4] = (bf16)p1[0]; o[5] = (bf16)p1[1]; o[6] = (bf16)p1[2]; o[7] = (bf16)p1[3];
        pf[g] = o;
      }
      const int chunk_lo = kc * 4 + (lg >> 1);
      const int rem = (lg & 1) * 4;              // elements
#pragma unroll
      for (int dt = 0; dt < 4; ++dt) {
        const int row = dt * 16 + r;
        const int sw = row & 7;
        const bf16* vlo = &Vs[buf][row * 64 + ((chunk_lo ^ sw) * 8) + rem];
        const bf16* vhi = &Vs[buf][row * 64 + (((chunk_lo + 2) ^ sw) * 8) + rem];
        bf16x4 lo = *reinterpret_cast<const bf16x4*>(vlo);
        bf16x4 hi = *reinterpret_cast<const bf16x4*>(vhi);
        bf16x8 vf;
        vf[0] = lo[0]; vf[1] = lo[1]; vf[2] = lo[2]; vf[3] = lo[3];
        vf[4] = hi[0]; vf[5] = hi[1]; vf[6] = hi[2]; vf[7] = hi[3];
#pragma unroll
        for (int g = 0; g < 2; ++g)
          ctx[g][dt] = MFMA_16x16x32(vf, pf[g], ctx[g][dt]);
      }
    }

    __syncthreads();   // drains vmcnt (next tile staged) + all waves done with buf
    buf ^= 1;
  }

#pragma unroll
  for (int g = 0; g < 2; ++g) {
    float l = lr[g];
    l += __shfl_xor(l, 16);
    l += __shfl_xor(l, 32);
    const float inv = 1.0f / l;
    float* obase = out + ((size_t)b * S + qbase + g * 16 + r) * H + h * DH;
#pragma unroll
    for (int dt = 0; dt < 4; ++dt) {
      float4 o;
      o.x = ctx[g][dt][0] * inv; o.y = ctx[g][dt][1] * inv;
      o.z = ctx[g][dt][2] * inv; o.w = ctx[g][dt][3] * inv;
      *reinterpret_cast<float4*>(obase + dt * 16 + lg * 4) = o;
    }
  }
}

extern "C" void kernel_launch(void* const* d_in, const int* in_sizes, int n_in,
                              void* d_out, int out_size, void* d_ws, size_t ws_size,
                              hipStream_t stream) {
  const float* hidden = (const float*)d_in[0];
  const float* mask   = (const float*)d_in[1];
  const float* Wq = (const float*)d_in[2];
  const float* bq = (const float*)d_in[3];
  const float* Wk = (const float*)d_in[4];
  const float* bk = (const float*)d_in[5];
  const float* Wv = (const float*)d_in[6];
  const float* bv = (const float*)d_in[7];
  const int* eidx = (const int*)d_in[8];

  if (ws_size < WS_NEED) return;

  char* ws = (char*)d_ws;
  bf16* Xb  = (bf16*)(ws + XB_OFF);
  bf16* Wqb = (bf16*)(ws + WQ_OFF);
  bf16* Wkb = (bf16*)(ws + WK_OFF);
  bf16* Wvb = (bf16*)(ws + WV_OFF);
  bf16* Qbf = (bf16*)(ws + QB_OFF);
  bf16* Kbf = (bf16*)(ws + KB_OFF);
  bf16* Vbf = (bf16*)(ws + VB_OFF);
  float* out = (float*)d_out;

  cvt_all<<<9984, 256, 0, stream>>>(hidden, Wq, Wk, Wv, Xb, Wqb, Wkb, Wvb);
  proj_gemm<<<768, 512, 0, stream>>>(Xb, Wqb, Wkb, Wvb, bq, bk, bv, eidx,
                                     Qbf, Kbf, Vbf);
  attn_kernel<<<768, 256, 0, stream>>>(Qbf, Kbf, Vbf, mask, out);
}